// Round 3
// baseline (2685.394 us; speedup 1.0000x reference)
//
#include <hip/hip_runtime.h>

typedef _Float16 f16;
typedef f16 f16x8 __attribute__((ext_vector_type(8)));
typedef f16 f16x2 __attribute__((ext_vector_type(2)));
typedef float f32x4 __attribute__((ext_vector_type(4)));
typedef unsigned long long u64;

#define MFMA16(a, b, c) __builtin_amdgcn_mfma_f32_16x16x32_f16(a, b, c, 0, 0, 0)
#define ROT 16

__device__ inline float fsig(float x) { return 1.f / (1.f + __expf(-x)); }
__device__ inline float ftanh(float x) {
    x = fminf(15.f, fmaxf(-15.f, x));
    float e = __expf(2.f * x);
    return (e - 1.f) / (e + 1.f);
}

// LLC-coherent (L2-bypassing) relaxed atomic ld/st
__device__ __forceinline__ void bstore8(void* p, u64 v) {
    __hip_atomic_store((u64*)p, v, __ATOMIC_RELAXED, __HIP_MEMORY_SCOPE_AGENT);
}
__device__ __forceinline__ void bstore4(float* p, float v) {
    __hip_atomic_store(p, v, __ATOMIC_RELAXED, __HIP_MEMORY_SCOPE_AGENT);
}
__device__ __forceinline__ float bload_f32(const float* p) {
    return __hip_atomic_load((float*)p, __ATOMIC_RELAXED, __HIP_MEMORY_SCOPE_AGENT);
}
__device__ __forceinline__ void fstore_u32(unsigned* p, unsigned v) {
    __hip_atomic_store(p, v, __ATOMIC_RELAXED, __HIP_MEMORY_SCOPE_AGENT);
}
__device__ __forceinline__ unsigned fload_u32(unsigned* p) {
    return __hip_atomic_load(p, __ATOMIC_RELAXED, __HIP_MEMORY_SCOPE_AGENT);
}
// LDS (workgroup-scope) flag ops
__device__ __forceinline__ void lstore_u32(unsigned* p, unsigned v) {
    __hip_atomic_store(p, v, __ATOMIC_RELAXED, __HIP_MEMORY_SCOPE_WORKGROUP);
}
__device__ __forceinline__ unsigned lload_u32(unsigned* p) {
    return __hip_atomic_load(p, __ATOMIC_RELAXED, __HIP_MEMORY_SCOPE_WORKGROUP);
}

// wait until all 64 flags >= e (one wave; lane = tid&63)
__device__ __forceinline__ void poll64x(unsigned* f, unsigned e, int lane) {
    for (;;) {
        unsigned v = fload_u32(f + lane);
        if (__all((int)(v >= e))) break;
        __builtin_amdgcn_s_sleep(2);
    }
    asm volatile("" ::: "memory");
}
// wait until 4 flags >= e (one wave)
__device__ __forceinline__ void poll4(unsigned* f, unsigned e, int lane) {
    for (;;) {
        unsigned v = fload_u32(f + (lane & 3));
        if (__all((int)(v >= e))) break;
        __builtin_amdgcn_s_sleep(1);
    }
    asm volatile("" ::: "memory");
}

// ---------------- one-time conversions + embedding pre-gather ----------------
__global__ __launch_bounds__(256) void k_convert(
    const float* __restrict__ Wih, const float* __restrict__ Whh,
    const float* __restrict__ W1, const float* __restrict__ W2,
    const float* __restrict__ bih, const float* __restrict__ bhh,
    const int* __restrict__ tgt, const float* __restrict__ emb,
    const float* __restrict__ henc,
    f16* __restrict__ wcat, f16* __restrict__ w1c, f16* __restrict__ w2a,
    f16* __restrict__ w2b, float* __restrict__ bsum, f16* __restrict__ Xall,
    f16* __restrict__ h16)
{
    const long NW = 16777216, NT = 1048576, NA = 524288, NB = 524288,
               NS = 8192, NX = 2097152, NH = 8388608;
    const long TOT = NW + NT + NA + NB + NS + NX + NH;
    for (long i = (long)blockIdx.x * 256 + threadIdx.x; i < TOT;
         i += (long)gridDim.x * 256) {
        if (i < NW) {
            long l = i >> 23;
            long r = i & 8388607;
            int j = (int)(r >> 11), k = (int)(r & 2047);
            float val = (k < 1024) ? Wih[(l * 4096 + j) * 1024 + k]
                                   : Whh[(l * 4096 + j) * 1024 + (k - 1024)];
            wcat[i] = (f16)val;
        } else if (i < NW + NT) {
            long r = i - NW;
            int h = (int)(r >> 10), v = (int)(r & 1023);
            w1c[r] = (f16)W1[(long)v * 1024 + h];
        } else if (i < NW + NT + NA) {
            long r = i - NW - NT;
            int e = (int)(r >> 10), v = (int)(r & 1023);
            w2a[r] = (f16)W2[(long)e * 2048 + v];
        } else if (i < NW + NT + NA + NB) {
            long r = i - NW - NT - NA;
            int e = (int)(r >> 10), k = (int)(r & 1023);
            w2b[r] = (f16)W2[(long)e * 2048 + 1024 + k];
        } else if (i < NW + NT + NA + NB + NS) {
            long r = i - NW - NT - NA - NB;
            bsum[r] = bih[r] + bhh[r];
        } else if (i < NW + NT + NA + NB + NS + NX) {
            long r = i - NW - NT - NA - NB - NS;
            int t = (int)(r >> 15), mm = (int)((r >> 9) & 63), k = (int)(r & 511);
            Xall[r] = (f16)emb[(long)tgt[t * 64 + mm] * 512 + k];
        } else {
            long r = i - NW - NT - NA - NB - NS - NX;
            h16[r] = (f16)henc[r];
        }
    }
}

// ---------------- state init ----------------
__global__ __launch_bounds__(256) void k_init(
    const float* __restrict__ oinit, const float* __restrict__ hinit,
    f16* __restrict__ O0, f16* __restrict__ H00, f16* __restrict__ H10,
    float* __restrict__ c01, unsigned* __restrict__ sync)
{
    int idx = blockIdx.x * 256 + threadIdx.x;
    if (idx < 32768) {
        O0[idx] = (f16)oinit[idx];
    } else if (idx < 98304) {
        H00[idx - 32768] = (f16)hinit[idx - 32768];
    } else if (idx < 163840) {
        H10[idx - 98304] = (f16)hinit[65536 + (idx - 98304)];
    } else if (idx < 294912) {
        c01[idx - 163840] = 0.f;
    } else if (idx < 297984) {
        sync[idx - 294912] = 0u;  // arr[256]|rel[256]|sflag[256]|zflag[64]|oflag[64]|...|cnt
    }
}

// ---------------- sb[b,s] = b1 . h_enc[b,s,:] ----------------
__global__ __launch_bounds__(256) void k_sb(
    const float* __restrict__ b1, const float* __restrict__ henc,
    float* __restrict__ sb)
{
    int bs = blockIdx.x * 256 + threadIdx.x;
    const float* hr = henc + (long)bs * 1024;
    float a = 0.f;
    for (int k = 0; k < 1024; k += 4) {
        float4 h4 = *(const float4*)(hr + k);
        float4 b4 = *(const float4*)(b1 + k);
        a += h4.x * b4.x + h4.y * b4.y + h4.z * b4.z + h4.w * b4.w;
    }
    sb[bs] = a;
}

// ---------------- GEMM: C[M,N](f16) = A16[M,1024] * B16[N,1024]^T ----------------
__global__ __launch_bounds__(256) void k_gemm(
    const f16* __restrict__ A, const f16* __restrict__ Bm,
    f16* __restrict__ C, int N)
{
    int nb = N >> 7;
    int bm = blockIdx.x / nb, bn = blockIdx.x % nb;
    int tid = threadIdx.x, w = tid >> 6, lane = tid & 63;
    int quad = lane >> 4, nn = lane & 15;
    const f16* ap = A + (long)(bm * 64 + w * 16 + nn) * 1024 + quad * 8;
    const f16* bp = Bm + (long)(bn * 128 + nn) * 1024 + quad * 8;
    f32x4 acc[8] = {};
    for (int kk = 0; kk < 1024; kk += 32) {
        f16x8 av = *(const f16x8*)(ap + kk);
        #pragma unroll
        for (int t2 = 0; t2 < 8; ++t2) {
            f16x8 bv = *(const f16x8*)(bp + (long)t2 * 16 * 1024 + kk);
            acc[t2] = MFMA16(av, bv, acc[t2]);
        }
    }
    #pragma unroll
    for (int t2 = 0; t2 < 8; ++t2)
        #pragma unroll
        for (int r = 0; r < 4; ++r) {
            int m = bm * 64 + w * 16 + quad * 4 + r;
            int col = bn * 128 + t2 * 16 + nn;
            C[(long)m * N + col] = (f16)acc[t2][r];
        }
}

// ---------------- grid barrier: store-arrivals + single-aggregator ----------------
__device__ __forceinline__ void gsync(unsigned* sync, unsigned e) {
    asm volatile("s_waitcnt vmcnt(0) lgkmcnt(0)" ::: "memory");
    __syncthreads();
    unsigned* arr = sync;
    unsigned* rel = sync + 256;
    if (threadIdx.x == 0)
        fstore_u32(arr + blockIdx.x, e);
    if (blockIdx.x == 0) {
        if (threadIdx.x < 64) {
            int lane = threadIdx.x;
            for (;;) {
                unsigned v0 = fload_u32(arr + lane);
                unsigned v1 = fload_u32(arr + 64 + lane);
                unsigned v2 = fload_u32(arr + 128 + lane);
                unsigned v3 = fload_u32(arr + 192 + lane);
                if (__all((int)(v0 >= e && v1 >= e && v2 >= e && v3 >= e)))
                    break;
                __builtin_amdgcn_s_sleep(1);
            }
            if (lane < 8) fstore_u32(rel + lane * 32, e);
        }
    } else if (threadIdx.x == 0) {
        unsigned* r = rel + (blockIdx.x & 7) * 32;
        while (fload_u32(r) < e)
            __builtin_amdgcn_s_sleep(2);
    }
    __syncthreads();
    asm volatile("" ::: "memory");
}

// ---------------- LSTM layer core: weights pinned in VGPRs ----------------
__device__ __forceinline__ void lstm_core(
    const f16* base, int rst, const f16x8* wreg,
    const float* __restrict__ bs_, float* __restrict__ c_,
    f16* __restrict__ dest, float* lds, int b, int tid)
{
    int w = tid >> 6, lane = tid & 63, quad = lane >> 4, n = lane & 15;
    const f16* ap = base + (long)n * rst + quad * 8;
    f32x4 acc0 = {}, acc1 = {}, acc2 = {}, acc3 = {};
    #pragma unroll
    for (int kk = 0; kk < 8; ++kk) {
        f16x8 bv = wreg[kk];
        f16x8 a0 = *(const f16x8*)(ap + kk * 32);
        f16x8 a1 = *(const f16x8*)(ap + (long)16 * rst + kk * 32);
        f16x8 a2 = *(const f16x8*)(ap + (long)32 * rst + kk * 32);
        f16x8 a3 = *(const f16x8*)(ap + (long)48 * rst + kk * 32);
        acc0 = MFMA16(a0, bv, acc0);
        acc1 = MFMA16(a1, bv, acc1);
        acc2 = MFMA16(a2, bv, acc2);
        acc3 = MFMA16(a3, bv, acc3);
    }
    #pragma unroll
    for (int r = 0; r < 4; ++r) {
        int mb = quad * 4 + r;
        lds[(w * 64 + mb) * 17 + n]      = acc0[r];
        lds[(w * 64 + 16 + mb) * 17 + n] = acc1[r];
        lds[(w * 64 + 32 + mb) * 17 + n] = acc2[r];
        lds[(w * 64 + 48 + mb) * 17 + n] = acc3[r];
    }
    __syncthreads();
    if (tid < 256) {
        int m = tid >> 2, uu = tid & 3;
        float s0 = 0.f, s1 = 0.f, s2 = 0.f, s3 = 0.f;
        #pragma unroll
        for (int ww = 0; ww < 8; ++ww) {
            const float* p = lds + (ww * 64 + m) * 17 + uu * 4;
            s0 += p[0]; s1 += p[1]; s2 += p[2]; s3 += p[3];
        }
        int ug = b * 4 + uu;
        float iv = fsig(s0 + bs_[ug]);
        float fv = fsig(s1 + bs_[1024 + ug]);
        float gv = ftanh(s2 + bs_[2048 + ug]);
        float ov = fsig(s3 + bs_[3072 + ug]);
        float cold = c_[m * 1024 + ug];
        float cn = fv * cold + iv * gv;
        float hn = ov * ftanh(cn);
        c_[m * 1024 + ug] = cn;
        lds[8704 + m * 4 + uu] = hn;
    }
    __syncthreads();
    if (tid < 64) {
        union { f16 h[4]; u64 u; } pk;
        #pragma unroll
        for (int uu = 0; uu < 4; ++uu) pk.h[uu] = (f16)lds[8704 + tid * 4 + uu];
        bstore8(dest + (long)tid * 1024 + b * 4, pk.u);
    }
}

// ---------------- Z1 half-K core (blocks 64..127) ----------------
__device__ __forceinline__ void z1_core(
    const f16* __restrict__ H1n, const f16x8* wz, const float* __restrict__ b2,
    float* __restrict__ Z1f, int bb, int khalf, float* lds, int tid)
{
    int w = tid >> 6, lane = tid & 63, quad = lane >> 4, n = lane & 15;
    const f16* ap = H1n + (long)n * 1024 + khalf * 512 + w * 64 + quad * 8;
    f32x4 acc0 = {}, acc1 = {}, acc2 = {}, acc3 = {};
    #pragma unroll
    for (int kk = 0; kk < 2; ++kk) {
        f16x8 bv = wz[kk];
        f16x8 a0 = *(const f16x8*)(ap + kk * 32);
        f16x8 a1 = *(const f16x8*)(ap + 16384 + kk * 32);
        f16x8 a2 = *(const f16x8*)(ap + 32768 + kk * 32);
        f16x8 a3 = *(const f16x8*)(ap + 49152 + kk * 32);
        acc0 = MFMA16(a0, bv, acc0);
        acc1 = MFMA16(a1, bv, acc1);
        acc2 = MFMA16(a2, bv, acc2);
        acc3 = MFMA16(a3, bv, acc3);
    }
    #pragma unroll
    for (int r = 0; r < 4; ++r) {
        int mb = quad * 4 + r;
        lds[(w * 64 + mb) * 17 + n]      = acc0[r];
        lds[(w * 64 + 16 + mb) * 17 + n] = acc1[r];
        lds[(w * 64 + 32 + mb) * 17 + n] = acc2[r];
        lds[(w * 64 + 48 + mb) * 17 + n] = acc3[r];
    }
    __syncthreads();
    int m = tid >> 3, n0 = (tid & 7) * 2;
    float s0 = 0.f, s1 = 0.f;
    #pragma unroll
    for (int ww = 0; ww < 8; ++ww) {
        const float* p = lds + (ww * 64 + m) * 17 + n0;
        s0 += p[0]; s1 += p[1];
    }
    int e = bb * 16 + n0;
    if (khalf == 0) { s0 += b2[e]; s1 += b2[e + 1]; }
    union { float f[2]; u64 u; } pk;
    pk.f[0] = s0; pk.f[1] = s1;
    bstore8(Z1f + khalf * 32768 + (long)m * 512 + e, pk.u);
}

// ---------------- persistent decoder ----------------
// Sync per step: B1 (full, after S1: H0n all-to-all), B2 (full, after S2:
// H1n all-to-all), then store-only flags:
//   sflag[b]  : Sc(t) drained           -> polled by same-m group in S4
//   zflag[64] : Z1f(t) drained          -> polled by winner's wave 0
//   oflag[m]  : Orot(t) drained         -> polled by wave 2 in S1(t+1),
//               handed to wave 3 via LDS flag
// WAR across steps: writes at t+1 happen after B2(t+1); arrival at B2(t+1)
// implies every block completed S4(t) reads in program order.
__global__ __launch_bounds__(512, 2) void k_persist(
    const f16* __restrict__ wcat, const float* __restrict__ bsum,
    float* __restrict__ c01, const f16* __restrict__ Xall,
    f16* __restrict__ Orot, f16* __restrict__ H0rot, f16* __restrict__ H1rot,
    const f16* __restrict__ P16, const f16* __restrict__ Q216,
    const f16* __restrict__ w2b, const float* __restrict__ sb,
    const float* __restrict__ b2, float* __restrict__ out,
    float* __restrict__ Z1f, float* __restrict__ Z2p,
    float* __restrict__ Sc, unsigned* __restrict__ sync)
{
    extern __shared__ float smem[];
    float* scr = smem;                      // 8960 floats scratch
    unsigned* ofd = (unsigned*)(smem + 8960); // LDS o-ready flag (wave2 -> wave3)
    f16* Pl  = (f16*)(smem + 8976);         // 32768 f16
    f16* Q2l = Pl + 32768;                  // 16384 f16

    int b = blockIdx.x, tid = threadIdx.x;
    int m = b >> 2, sq = b & 3;
    int wv = tid >> 6, lane = tid & 63, quad = lane >> 4, nn = lane & 15;

    unsigned* sflag = sync + 512;           // [512..768)
    unsigned* zflag = sync + 768;           // [768..832)
    unsigned* oflag = sync + 832;           // [832..896)
    unsigned* cnt   = sync + 1024;          // 64 counters, 32-u32 stride

    const bool zb = (b >= 64 && b < 128);

    // -------- prologue: pin weights in VGPRs, P/Q2 slices in LDS --------
    f16x8 w0[8], w1[8];
    {
        int j0 = (nn & 3) * 1024 + b * 4 + (nn >> 2);
        const f16* wp = wcat + (long)j0 * 2048 + wv * 256 + quad * 8;
        #pragma unroll
        for (int kk = 0; kk < 8; ++kk) {
            w0[kk] = *(const f16x8*)(wp + kk * 32);
            w1[kk] = *(const f16x8*)(wp + 8388608 + kk * 32);
        }
    }
    f16x8 wz[2];
    if (zb) {
        int zz = b - 64, bb = zz & 31, kh = zz >> 5;
        int j = bb * 16 + nn;
        const f16* zp = w2b + (long)j * 1024 + kh * 512 + wv * 64 + quad * 8;
        #pragma unroll
        for (int kk = 0; kk < 2; ++kk) wz[kk] = *(const f16x8*)(zp + kk * 32);
    }
    {
        const uint4* gp = (const uint4*)(P16 + ((long)(m * 128 + sq * 32)) * 1024);
        #pragma unroll
        for (int i = 0; i < 8; ++i) ((uint4*)Pl)[i * 512 + tid] = gp[i * 512 + tid];
        const uint4* gq = (const uint4*)(Q216 + ((long)(m * 128 + sq * 32)) * 512);
        #pragma unroll
        for (int i = 0; i < 4; ++i) ((uint4*)Q2l)[i * 512 + tid] = gq[i * 512 + tid];
    }
    if (tid == 0) lstore_u32(ofd, 0u);
    __syncthreads();

    unsigned epoch = 0;
    for (int t = 0; t < 64; ++t) {
        int rs0 = t & (ROT - 1), rs1 = (t + 1) & (ROT - 1);
        const f16* Xc = Xall + (long)t * 32768;
        const f16* Oc = Orot + (long)rs0 * 32768;
        const f16* H0c = H0rot + (long)rs0 * 65536;
        f16* H0n = H0rot + (long)rs1 * 65536;
        const f16* H1c = H1rot + (long)rs0 * 65536;
        f16* H1n = H1rot + (long)rs1 * 65536;

        // ---- S1: layer 0, K = [x(512) | o(512) | h0prev(1024)] ----
        {
            const f16* base; int rst;
            if (wv < 2)      { base = Xc + wv * 256;        rst = 512; }
            else if (wv < 4) { base = Oc + (wv - 2) * 256;  rst = 512; }
            else             { base = H0c + (wv - 4) * 256; rst = 1024; }
            // gate O-consuming waves on the 64 winners of step t-1
            if (wv == 2) {
                poll64x(oflag, (unsigned)t, lane);
                if (lane == 0) lstore_u32(ofd, (unsigned)(t + 1));
            } else if (wv == 3) {
                while (lload_u32(ofd) < (unsigned)(t + 1))
                    __builtin_amdgcn_s_sleep(1);
                asm volatile("" ::: "memory");
            }
            lstm_core(base, rst, w0, bsum, c01, H0n, scr, b, tid);
        }
        gsync(sync, ++epoch);   // B1: H0n all-to-all

        // ---- S2: layer 1, K = [h0(1024) | h1prev(1024)] ----
        {
            const f16* base = (wv < 4) ? (H0n + wv * 256) : (H1c + (wv - 4) * 256);
            lstm_core(base, 1024, w1, bsum + 4096, c01 + 65536, H1n, scr, b, tid);
        }
        gsync(sync, ++epoch);   // B2: H1n all-to-all

        // ---- S3: scores (all blocks) + Z1 halves (blocks 64..127) ----
        {
            f16* h1l = (f16*)scr;
            if (tid < 128)
                ((uint4*)h1l)[tid] = *(const uint4*)(H1n + (long)m * 1024 + tid * 8);
            __syncthreads();
            int sl = tid >> 4, kc = tid & 15;
            const f16* prow = Pl + sl * 1024;
            float a0 = 0.f;
            #pragma unroll
            for (int i = 0; i < 8; ++i) {
                int ch = (i * 16 + kc) * 8;
                f16x8 pv = *(const f16x8*)(prow + ch);
                f16x8 hv = *(const f16x8*)(h1l + ch);
                #pragma unroll
                for (int p2 = 0; p2 < 4; ++p2) {
                    f16x2 pa = { pv[p2 * 2], pv[p2 * 2 + 1] };
                    f16x2 ha = { hv[p2 * 2], hv[p2 * 2 + 1] };
                    a0 = __builtin_amdgcn_fdot2(pa, ha, a0, false);
                }
            }
            #pragma unroll
            for (int off = 8; off; off >>= 1) a0 += __shfl_xor(a0, off, 16);
            if (kc == 0)
                bstore4(Sc + m * 128 + sq * 32 + sl, a0 + sb[m * 128 + sq * 32 + sl]);
            asm volatile("s_waitcnt vmcnt(0)" ::: "memory");  // Sc drained (all threads)
            __syncthreads();
            if (tid == 0) fstore_u32(sflag + b, (unsigned)(t + 1));
            if (zb) {
                z1_core(H1n, wz, b2, Z1f, (b - 64) & 31, (b - 64) >> 5, scr, tid);
                asm volatile("s_waitcnt vmcnt(0)" ::: "memory");  // Z1f drained
                __syncthreads();
                if (tid == 0) fstore_u32(zflag + (b - 64), (unsigned)(t + 1));
            }
        }
        // no full barrier: S4 gates on sflag (own group) / zflag (winner)

        // ---- S4: softmax + Z2 partial + winner finish ----
        {
            if (wv < 2) poll4(sflag + m * 4, (unsigned)(t + 1), lane);
            if (tid < 128) scr[tid] = bload_f32(Sc + m * 128 + tid);
            __syncthreads();
            if (tid < 64) {
                float v = fmaxf(scr[tid], scr[64 + tid]);
                #pragma unroll
                for (int off = 32; off; off >>= 1) v = fmaxf(v, __shfl_down(v, off));
                if (tid == 0) scr[128] = v;
            }
            __syncthreads();
            if (tid < 128) scr[tid] = __expf(scr[tid] - scr[128]);
            __syncthreads();
            if (tid < 64) {
                float v = scr[tid] + scr[64 + tid];
                #pragma unroll
                for (int off = 32; off; off >>= 1) v += __shfl_down(v, off);
                if (tid == 0) scr[129] = 1.f / v;
            }
            __syncthreads();
            float inv = scr[129];
            float zp = 0.f;
            #pragma unroll 8
            for (int jy = 0; jy < 32; ++jy)
                zp += scr[sq * 32 + jy] * (float)Q2l[jy * 512 + tid];
            bstore4(Z2p + ((m * 4 + sq) << 9) + tid, zp * inv);
            asm volatile("s_waitcnt vmcnt(0)" ::: "memory");
            __syncthreads();
            if (tid == 0) {
                unsigned old = __hip_atomic_fetch_add(cnt + m * 32, 1u,
                        __ATOMIC_RELAXED, __HIP_MEMORY_SCOPE_AGENT);
                scr[130] = (old == (unsigned)(4 * t + 3)) ? 1.f : 0.f;
            }
            __syncthreads();
            if (scr[130] != 0.f) {
                if (wv == 0) poll64x(zflag, (unsigned)(t + 1), lane);
                __syncthreads();
                float z = bload_f32(Z1f + (m << 9) + tid)
                        + bload_f32(Z1f + 32768 + (m << 9) + tid);
                #pragma unroll
                for (int q = 0; q < 4; ++q)
                    z += bload_f32(Z2p + ((m * 4 + q) << 9) + tid);
                float o = ftanh(z);
                out[((long)m * 64 + t) * 512 + tid] = o;
                f16* ob = (f16*)(scr + 192);
                ob[tid] = (f16)o;
                __syncthreads();
                if (tid < 128) {
                    union { f16 h[4]; u64 u; } pk;
                    #pragma unroll
                    for (int i = 0; i < 4; ++i) pk.h[i] = ob[tid * 4 + i];
                    bstore8(Orot + (long)rs1 * 32768 + m * 512 + tid * 4, pk.u);
                }
                if (wv < 2) asm volatile("s_waitcnt vmcnt(0)" ::: "memory");
                __syncthreads();
                if (tid == 0) fstore_u32(oflag + m, (unsigned)(t + 1));
            }
        }
        // no full barrier: S1(t+1) gates on oflag; WAR covered by B1/B2
    }
}

extern "C" void kernel_launch(void* const* d_in, const int* in_sizes, int n_in,
                              void* d_out, int out_size, void* d_ws, size_t ws_size,
                              hipStream_t stream)
{
    const int*   tgt   = (const int*)d_in[0];
    const float* henc  = (const float*)d_in[1];
    const float* emb   = (const float*)d_in[2];
    const float* oinit = (const float*)d_in[3];
    const float* hinit = (const float*)d_in[4];
    const float* Wih   = (const float*)d_in[5];
    const float* Whh   = (const float*)d_in[6];
    const float* bih   = (const float*)d_in[7];
    const float* bhh   = (const float*)d_in[8];
    const float* W1    = (const float*)d_in[9];
    const float* b1    = (const float*)d_in[10];
    const float* W2    = (const float*)d_in[11];
    const float* b2    = (const float*)d_in[12];
    float* out = (float*)d_out;

    char* ws = (char*)d_ws;
    f16*      wcat  = (f16*)(ws + 0);              // 32 MB
    f16*      P16   = (f16*)(ws + 33554432);       // 16 MB
    f16*      Q216  = (f16*)(ws + 50331648);       //  8 MB
    f16*      h16   = (f16*)(ws + 58720256);       // 16 MB
    f16*      w2b   = (f16*)(ws + 75497472);       //  1 MB
    f16*      w1c   = (f16*)(ws + 76546048);       //  2 MB
    f16*      w2a   = (f16*)(ws + 78643200);       //  1 MB
    f16*      Xall  = (f16*)(ws + 79691776);       //  4 MB
    f16*      H0rot = (f16*)(ws + 83886080);       //  2 MB (16 slots)
    f16*      H1rot = (f16*)(ws + 85983232);       //  2 MB
    f16*      Orot  = (f16*)(ws + 88080384);       //  1 MB
    float*    c01   = (float*)(ws + 89128960);     // 512 KB
    float*    Z1f   = (float*)(ws + 89653248);     // 256 KB (2 halves)
    float*    Z2p   = (float*)(ws + 89915392);     // 512 KB
    float*    Sc    = (float*)(ws + 90439680);     //  32 KB
    float*    bsum  = (float*)(ws + 90472448);     //  32 KB
    float*    sb    = (float*)(ws + 90505216);     //  32 KB
    unsigned* sync  = (unsigned*)(ws + 90537984);  //  12 KB: arr|rel|flags|cnt

    hipLaunchKernelGGL(k_convert, dim3(4096), dim3(256), 0, stream,
                       Wih, Whh, W1, W2, bih, bhh, tgt, emb, henc,
                       wcat, w1c, w2a, w2b, bsum, Xall, h16);
    hipLaunchKernelGGL(k_init, dim3(1164), dim3(256), 0, stream,
                       oinit, hinit, Orot, H0rot, H1rot, c01, sync);
    hipLaunchKernelGGL(k_sb, dim3(32), dim3(256), 0, stream, b1, henc, sb);
    hipLaunchKernelGGL(k_gemm, dim3(128 * 8), dim3(256), 0, stream,
                       h16, w1c, P16, 1024);
    hipLaunchKernelGGL(k_gemm, dim3(128 * 4), dim3(256), 0, stream,
                       h16, w2a, Q216, 512);

    static const unsigned LDS_BYTES = 8976 * 4 + 32768 * 2 + 16384 * 2; // 134208
    hipFuncSetAttribute((const void*)k_persist,
                        hipFuncAttributeMaxDynamicSharedMemorySize, LDS_BYTES);
    void* args[] = { &wcat, &bsum, &c01, &Xall, &Orot, &H0rot, &H1rot, &P16,
                     &Q216, &w2b, &sb, &b2, &out, &Z1f, &Z2p, &Sc, &sync };
    hipLaunchCooperativeKernel((const void*)k_persist, dim3(256), dim3(512),
                               args, LDS_BYTES, stream);
}

// Round 4
// 2234.488 us; speedup vs baseline: 1.2018x; 1.2018x over previous
//
#include <hip/hip_runtime.h>

typedef _Float16 f16;
typedef f16 f16x8 __attribute__((ext_vector_type(8)));
typedef f16 f16x2 __attribute__((ext_vector_type(2)));
typedef float f32x4 __attribute__((ext_vector_type(4)));
typedef unsigned long long u64;

#define MFMA16(a, b, c) __builtin_amdgcn_mfma_f32_16x16x32_f16(a, b, c, 0, 0, 0)
#define ROT 16

__device__ inline float fsig(float x) { return 1.f / (1.f + __expf(-x)); }
__device__ inline float ftanh(float x) {
    x = fminf(15.f, fmaxf(-15.f, x));
    float e = __expf(2.f * x);
    return (e - 1.f) / (e + 1.f);
}

// LLC-coherent (L2-bypassing) relaxed atomic ld/st
__device__ __forceinline__ void bstore8(void* p, u64 v) {
    __hip_atomic_store((u64*)p, v, __ATOMIC_RELAXED, __HIP_MEMORY_SCOPE_AGENT);
}
__device__ __forceinline__ void bstore4(float* p, float v) {
    __hip_atomic_store(p, v, __ATOMIC_RELAXED, __HIP_MEMORY_SCOPE_AGENT);
}
__device__ __forceinline__ float bload_f32(const float* p) {
    return __hip_atomic_load((float*)p, __ATOMIC_RELAXED, __HIP_MEMORY_SCOPE_AGENT);
}
__device__ __forceinline__ void fstore_u32(unsigned* p, unsigned v) {
    __hip_atomic_store(p, v, __ATOMIC_RELAXED, __HIP_MEMORY_SCOPE_AGENT);
}
__device__ __forceinline__ unsigned fload_u32(unsigned* p) {
    return __hip_atomic_load(p, __ATOMIC_RELAXED, __HIP_MEMORY_SCOPE_AGENT);
}

// ---------------- one-time conversions + embedding pre-gather ----------------
__global__ __launch_bounds__(256) void k_convert(
    const float* __restrict__ Wih, const float* __restrict__ Whh,
    const float* __restrict__ W1, const float* __restrict__ W2,
    const float* __restrict__ bih, const float* __restrict__ bhh,
    const int* __restrict__ tgt, const float* __restrict__ emb,
    const float* __restrict__ henc,
    f16* __restrict__ wcat, f16* __restrict__ w1c, f16* __restrict__ w2a,
    f16* __restrict__ w2b, float* __restrict__ bsum, f16* __restrict__ Xall,
    f16* __restrict__ h16)
{
    const long NW = 16777216, NT = 1048576, NA = 524288, NB = 524288,
               NS = 8192, NX = 2097152, NH = 8388608;
    const long TOT = NW + NT + NA + NB + NS + NX + NH;
    for (long i = (long)blockIdx.x * 256 + threadIdx.x; i < TOT;
         i += (long)gridDim.x * 256) {
        if (i < NW) {
            long l = i >> 23;
            long r = i & 8388607;
            int j = (int)(r >> 11), k = (int)(r & 2047);
            float val = (k < 1024) ? Wih[(l * 4096 + j) * 1024 + k]
                                   : Whh[(l * 4096 + j) * 1024 + (k - 1024)];
            wcat[i] = (f16)val;
        } else if (i < NW + NT) {
            long r = i - NW;
            int h = (int)(r >> 10), v = (int)(r & 1023);
            w1c[r] = (f16)W1[(long)v * 1024 + h];
        } else if (i < NW + NT + NA) {
            long r = i - NW - NT;
            int e = (int)(r >> 10), v = (int)(r & 1023);
            w2a[r] = (f16)W2[(long)e * 2048 + v];
        } else if (i < NW + NT + NA + NB) {
            long r = i - NW - NT - NA;
            int e = (int)(r >> 10), k = (int)(r & 1023);
            w2b[r] = (f16)W2[(long)e * 2048 + 1024 + k];
        } else if (i < NW + NT + NA + NB + NS) {
            long r = i - NW - NT - NA - NB;
            bsum[r] = bih[r] + bhh[r];
        } else if (i < NW + NT + NA + NB + NS + NX) {
            long r = i - NW - NT - NA - NB - NS;
            int t = (int)(r >> 15), mm = (int)((r >> 9) & 63), k = (int)(r & 511);
            Xall[r] = (f16)emb[(long)tgt[t * 64 + mm] * 512 + k];
        } else {
            long r = i - NW - NT - NA - NB - NS - NX;
            h16[r] = (f16)henc[r];
        }
    }
}

// ---------------- state init ----------------
__global__ __launch_bounds__(256) void k_init(
    const float* __restrict__ oinit, const float* __restrict__ hinit,
    f16* __restrict__ O0, f16* __restrict__ H00, f16* __restrict__ H10,
    float* __restrict__ c01, unsigned* __restrict__ sync)
{
    int idx = blockIdx.x * 256 + threadIdx.x;
    if (idx < 32768) {
        O0[idx] = (f16)oinit[idx];
    } else if (idx < 98304) {
        H00[idx - 32768] = (f16)hinit[idx - 32768];
    } else if (idx < 163840) {
        H10[idx - 98304] = (f16)hinit[65536 + (idx - 98304)];
    } else if (idx < 294912) {
        c01[idx - 163840] = 0.f;
    } else if (idx < 297984) {
        sync[idx - 294912] = 0u;    // arr[256] | rel[8x32] | pad
    }
}

// ---------------- sb[b,s] = b1 . h_enc[b,s,:] ----------------
__global__ __launch_bounds__(256) void k_sb(
    const float* __restrict__ b1, const float* __restrict__ henc,
    float* __restrict__ sb)
{
    int bs = blockIdx.x * 256 + threadIdx.x;
    const float* hr = henc + (long)bs * 1024;
    float a = 0.f;
    for (int k = 0; k < 1024; k += 4) {
        float4 h4 = *(const float4*)(hr + k);
        float4 b4 = *(const float4*)(b1 + k);
        a += h4.x * b4.x + h4.y * b4.y + h4.z * b4.z + h4.w * b4.w;
    }
    sb[bs] = a;
}

// ---------------- GEMM: C[M,N](f16) = A16[M,1024] * B16[N,1024]^T ----------------
__global__ __launch_bounds__(256) void k_gemm(
    const f16* __restrict__ A, const f16* __restrict__ Bm,
    f16* __restrict__ C, int N)
{
    int nb = N >> 7;
    int bm = blockIdx.x / nb, bn = blockIdx.x % nb;
    int tid = threadIdx.x, w = tid >> 6, lane = tid & 63;
    int quad = lane >> 4, nn = lane & 15;
    const f16* ap = A + (long)(bm * 64 + w * 16 + nn) * 1024 + quad * 8;
    const f16* bp = Bm + (long)(bn * 128 + nn) * 1024 + quad * 8;
    f32x4 acc[8] = {};
    for (int kk = 0; kk < 1024; kk += 32) {
        f16x8 av = *(const f16x8*)(ap + kk);
        #pragma unroll
        for (int t2 = 0; t2 < 8; ++t2) {
            f16x8 bv = *(const f16x8*)(bp + (long)t2 * 16 * 1024 + kk);
            acc[t2] = MFMA16(av, bv, acc[t2]);
        }
    }
    #pragma unroll
    for (int t2 = 0; t2 < 8; ++t2)
        #pragma unroll
        for (int r = 0; r < 4; ++r) {
            int m = bm * 64 + w * 16 + quad * 4 + r;
            int col = bn * 128 + t2 * 16 + nn;
            C[(long)m * N + col] = (f16)acc[t2][r];
        }
}

// ---------------- grid barrier: store-arrivals + single-aggregator ----------------
__device__ __forceinline__ void gsync(unsigned* sync, unsigned e) {
    asm volatile("s_waitcnt vmcnt(0) lgkmcnt(0)" ::: "memory");
    __syncthreads();
    unsigned* arr = sync;
    unsigned* rel = sync + 256;
    if (threadIdx.x == 0)
        fstore_u32(arr + blockIdx.x, e);
    if (blockIdx.x == 0) {
        if (threadIdx.x < 64) {
            int lane = threadIdx.x;
            for (;;) {
                unsigned v0 = fload_u32(arr + lane);
                unsigned v1 = fload_u32(arr + 64 + lane);
                unsigned v2 = fload_u32(arr + 128 + lane);
                unsigned v3 = fload_u32(arr + 192 + lane);
                if (__all((int)(v0 >= e && v1 >= e && v2 >= e && v3 >= e)))
                    break;
                __builtin_amdgcn_s_sleep(1);
            }
            if (lane < 8) fstore_u32(rel + lane * 32, e);
        }
    } else if (threadIdx.x == 0) {
        unsigned* r = rel + (blockIdx.x & 7) * 32;
        while (fload_u32(r) < e)
            __builtin_amdgcn_s_sleep(2);
    }
    __syncthreads();
    asm volatile("" ::: "memory");
}

// ---------------- LSTM layer core: weights pinned in VGPRs ----------------
__device__ __forceinline__ void lstm_core(
    const f16* base, int rst, const f16x8* wreg,
    const float* __restrict__ bs_, float* __restrict__ c_,
    f16* __restrict__ dest, float* lds, int b, int tid)
{
    int w = tid >> 6, lane = tid & 63, quad = lane >> 4, n = lane & 15;
    const f16* ap = base + (long)n * rst + quad * 8;
    f32x4 acc0 = {}, acc1 = {}, acc2 = {}, acc3 = {};
    #pragma unroll
    for (int kk = 0; kk < 8; ++kk) {
        f16x8 bv = wreg[kk];
        f16x8 a0 = *(const f16x8*)(ap + kk * 32);
        f16x8 a1 = *(const f16x8*)(ap + (long)16 * rst + kk * 32);
        f16x8 a2 = *(const f16x8*)(ap + (long)32 * rst + kk * 32);
        f16x8 a3 = *(const f16x8*)(ap + (long)48 * rst + kk * 32);
        acc0 = MFMA16(a0, bv, acc0);
        acc1 = MFMA16(a1, bv, acc1);
        acc2 = MFMA16(a2, bv, acc2);
        acc3 = MFMA16(a3, bv, acc3);
    }
    #pragma unroll
    for (int r = 0; r < 4; ++r) {
        int mb = quad * 4 + r;
        lds[(w * 64 + mb) * 17 + n]      = acc0[r];
        lds[(w * 64 + 16 + mb) * 17 + n] = acc1[r];
        lds[(w * 64 + 32 + mb) * 17 + n] = acc2[r];
        lds[(w * 64 + 48 + mb) * 17 + n] = acc3[r];
    }
    __syncthreads();
    if (tid < 256) {
        int m = tid >> 2, uu = tid & 3;
        float s0 = 0.f, s1 = 0.f, s2 = 0.f, s3 = 0.f;
        #pragma unroll
        for (int ww = 0; ww < 8; ++ww) {
            const float* p = lds + (ww * 64 + m) * 17 + uu * 4;
            s0 += p[0]; s1 += p[1]; s2 += p[2]; s3 += p[3];
        }
        int ug = b * 4 + uu;
        float iv = fsig(s0 + bs_[ug]);
        float fv = fsig(s1 + bs_[1024 + ug]);
        float gv = ftanh(s2 + bs_[2048 + ug]);
        float ov = fsig(s3 + bs_[3072 + ug]);
        float cold = c_[m * 1024 + ug];
        float cn = fv * cold + iv * gv;
        float hn = ov * ftanh(cn);
        c_[m * 1024 + ug] = cn;
        lds[8704 + m * 4 + uu] = hn;
    }
    __syncthreads();
    if (tid < 64) {
        union { f16 h[4]; u64 u; } pk;
        #pragma unroll
        for (int uu = 0; uu < 4; ++uu) pk.h[uu] = (f16)lds[8704 + tid * 4 + uu];
        bstore8(dest + (long)tid * 1024 + b * 4, pk.u);
    }
}

// ---------------- Z1 quarter-K core (blocks 0..127: er=b&31, kq=b>>5) ----------------
// Z1f[kq][m][e]: Z1f + kq*32768 + m*512 + e; bias added in kq==0 slice.
__device__ __forceinline__ void z1q(
    const f16* __restrict__ H1n, f16x8 wz, const float* __restrict__ b2,
    float* __restrict__ Z1f, int er, int kq, float* lds, int tid)
{
    int w = tid >> 6, lane = tid & 63, quad = lane >> 4, n = lane & 15;
    const f16* ap = H1n + (long)n * 1024 + kq * 256 + w * 32 + quad * 8;
    f32x4 acc0 = {}, acc1 = {}, acc2 = {}, acc3 = {};
    f16x8 a0 = *(const f16x8*)(ap);
    f16x8 a1 = *(const f16x8*)(ap + 16384);
    f16x8 a2 = *(const f16x8*)(ap + 32768);
    f16x8 a3 = *(const f16x8*)(ap + 49152);
    acc0 = MFMA16(a0, wz, acc0);
    acc1 = MFMA16(a1, wz, acc1);
    acc2 = MFMA16(a2, wz, acc2);
    acc3 = MFMA16(a3, wz, acc3);
    #pragma unroll
    for (int r = 0; r < 4; ++r) {
        int mb = quad * 4 + r;
        lds[(w * 64 + mb) * 17 + n]      = acc0[r];
        lds[(w * 64 + 16 + mb) * 17 + n] = acc1[r];
        lds[(w * 64 + 32 + mb) * 17 + n] = acc2[r];
        lds[(w * 64 + 48 + mb) * 17 + n] = acc3[r];
    }
    __syncthreads();
    int mm = tid >> 3, n0 = (tid & 7) * 2;
    float s0 = 0.f, s1 = 0.f;
    #pragma unroll
    for (int ww = 0; ww < 8; ++ww) {
        const float* p = lds + (ww * 64 + mm) * 17 + n0;
        s0 += p[0]; s1 += p[1];
    }
    int e = er * 16 + n0;
    if (kq == 0) { s0 += b2[e]; s1 += b2[e + 1]; }
    union { float f[2]; u64 u; } pk;
    pk.f[0] = s0; pk.f[1] = s1;
    bstore8(Z1f + kq * 32768 + (long)mm * 512 + e, pk.u);
}

// ---------------- persistent decoder ----------------
// 4 full gsyncs/step (R2's proven mechanism). S3 does local softmax +
// unnormalized Z2 partial (flash-style: combine with per-group scalar pairs
// after B3); Z1 split over blocks 0..127 (K-quarters); output finish
// distributed over the group's 4 blocks (e-128 quarter each). No elections,
// no cross-block score exchange, no flag protocols.
__global__ __launch_bounds__(512, 2) void k_persist(
    const f16* __restrict__ wcat, const float* __restrict__ bsum,
    float* __restrict__ c01, const f16* __restrict__ Xall,
    f16* __restrict__ Orot, f16* __restrict__ H0rot, f16* __restrict__ H1rot,
    const f16* __restrict__ P16, const f16* __restrict__ Q216,
    const f16* __restrict__ w2b, const float* __restrict__ sb,
    const float* __restrict__ b2, float* __restrict__ out,
    float* __restrict__ Z1f, float* __restrict__ Z2p,
    float* __restrict__ Z2s, unsigned* __restrict__ sync)
{
    extern __shared__ float smem[];
    float* scr = smem;                    // [0..8704) mfma-reduce, [8704..8960) small scratch
    f16* h1l = (f16*)(smem + 8960);       // 1024 f16
    f16* Pl  = (f16*)(smem + 9472);       // 32768 f16
    f16* Q2l = Pl + 32768;                // 16384 f16

    int b = blockIdx.x, tid = threadIdx.x;
    int m = b >> 2, sq = b & 3;
    int wv = tid >> 6, lane = tid & 63, quad = lane >> 4, nn = lane & 15;

    // -------- prologue: pin weights in VGPRs, P/Q2 slices in LDS --------
    f16x8 w0[8], w1[8];
    {
        int j0 = (nn & 3) * 1024 + b * 4 + (nn >> 2);
        const f16* wp = wcat + (long)j0 * 2048 + wv * 256 + quad * 8;
        #pragma unroll
        for (int kk = 0; kk < 8; ++kk) {
            w0[kk] = *(const f16x8*)(wp + kk * 32);
            w1[kk] = *(const f16x8*)(wp + 8388608 + kk * 32);
        }
    }
    f16x8 wz = {};
    if (b < 128) {
        int er = b & 31, kq = b >> 5;
        const f16* zp = w2b + (long)(er * 16 + nn) * 1024 + kq * 256 + wv * 32 + quad * 8;
        wz = *(const f16x8*)zp;
    }
    {
        const uint4* gp = (const uint4*)(P16 + ((long)(m * 128 + sq * 32)) * 1024);
        #pragma unroll
        for (int i = 0; i < 8; ++i) ((uint4*)Pl)[i * 512 + tid] = gp[i * 512 + tid];
        const uint4* gq = (const uint4*)(Q216 + ((long)(m * 128 + sq * 32)) * 512);
        #pragma unroll
        for (int i = 0; i < 4; ++i) ((uint4*)Q2l)[i * 512 + tid] = gq[i * 512 + tid];
    }
    __syncthreads();

    unsigned epoch = 0;
    for (int t = 0; t < 64; ++t) {
        int rs0 = t & (ROT - 1), rs1 = (t + 1) & (ROT - 1);
        const f16* Xc = Xall + (long)t * 32768;
        const f16* Oc = Orot + (long)rs0 * 32768;
        const f16* H0c = H0rot + (long)rs0 * 65536;
        f16* H0n = H0rot + (long)rs1 * 65536;
        const f16* H1c = H1rot + (long)rs0 * 65536;
        f16* H1n = H1rot + (long)rs1 * 65536;

        // ---- S1: layer 0, K = [x(512) | o(512) | h0prev(1024)] ----
        {
            const f16* base; int rst;
            if (wv < 2)      { base = Xc + wv * 256;        rst = 512; }
            else if (wv < 4) { base = Oc + (wv - 2) * 256;  rst = 512; }
            else             { base = H0c + (wv - 4) * 256; rst = 1024; }
            lstm_core(base, rst, w0, bsum, c01, H0n, scr, b, tid);
        }
        gsync(sync, ++epoch);   // B1

        // ---- S2: layer 1, K = [h0(1024) | h1prev(1024)] ----
        {
            const f16* base = (wv < 4) ? (H0n + wv * 256) : (H1c + (wv - 4) * 256);
            lstm_core(base, 1024, w1, bsum + 4096, c01 + 65536, H1n, scr, b, tid);
        }
        gsync(sync, ++epoch);   // B2

        // ---- S3: h1 gather + Z1 quarter + scores + local softmax + Z2 partial ----
        {
            if (tid < 128)
                ((uint4*)h1l)[tid] = *(const uint4*)(H1n + (long)m * 1024 + tid * 8);
            if (b < 128)
                z1q(H1n, wz, b2, Z1f, b & 31, b >> 5, scr, tid);
            __syncthreads();
            int sl = tid >> 4, kc = tid & 15;
            const f16* prow = Pl + sl * 1024;
            float a0 = 0.f;
            #pragma unroll
            for (int i = 0; i < 8; ++i) {
                int ch = (i * 16 + kc) * 8;
                f16x8 pv = *(const f16x8*)(prow + ch);
                f16x8 hv = *(const f16x8*)(h1l + ch);
                #pragma unroll
                for (int p2 = 0; p2 < 4; ++p2) {
                    f16x2 pa = { pv[p2 * 2], pv[p2 * 2 + 1] };
                    f16x2 ha = { hv[p2 * 2], hv[p2 * 2 + 1] };
                    a0 = __builtin_amdgcn_fdot2(pa, ha, a0, false);
                }
            }
            #pragma unroll
            for (int off = 8; off; off >>= 1) a0 += __shfl_xor(a0, off, 16);
            if (kc == 0)
                scr[8704 + sl] = a0 + sb[m * 128 + sq * 32 + sl];
            __syncthreads();
            if (tid < 32) {
                float v = scr[8704 + tid];
                float mx = v;
                #pragma unroll
                for (int off = 16; off; off >>= 1) mx = fmaxf(mx, __shfl_xor(mx, off));
                float ev = __expf(v - mx);
                float sm = ev;
                #pragma unroll
                for (int off = 16; off; off >>= 1) sm += __shfl_xor(sm, off);
                scr[8704 + tid] = ev;
                if (tid == 0) {
                    union { float f[2]; u64 u; } pk;
                    pk.f[0] = mx; pk.f[1] = sm;
                    bstore8(Z2s + ((m * 4 + sq) << 1), pk.u);
                }
            }
            __syncthreads();
            float zp = 0.f;
            #pragma unroll 8
            for (int jy = 0; jy < 32; ++jy)
                zp += scr[8704 + jy] * (float)Q2l[jy * 512 + tid];
            bstore4(Z2p + ((m * 4 + sq) << 9) + tid, zp);
        }
        gsync(sync, ++epoch);   // B3 (drains Z1f/Z2p/Z2s)

        // ---- S4: distributed finish — block (m,sq) does e-quarter sq*128.. ----
        {
            if (tid < 8) scr[8744 + tid] = bload_f32(Z2s + m * 8 + tid);
            __syncthreads();
            if (tid < 128) {
                float m0 = scr[8744], s0q = scr[8745], m1 = scr[8746], s1q = scr[8747],
                      m2 = scr[8748], s2q = scr[8749], m3 = scr[8750], s3q = scr[8751];
                float M = fmaxf(fmaxf(m0, m1), fmaxf(m2, m3));
                float q0 = __expf(m0 - M), q1 = __expf(m1 - M),
                      q2 = __expf(m2 - M), q3 = __expf(m3 - M);
                float den = q0 * s0q + q1 * s1q + q2 * s2q + q3 * s3q;
                int e = sq * 128 + tid;
                float z = bload_f32(Z1f + (m << 9) + e)
                        + bload_f32(Z1f + 32768 + (m << 9) + e)
                        + bload_f32(Z1f + 65536 + (m << 9) + e)
                        + bload_f32(Z1f + 98304 + (m << 9) + e);
                float num = q0 * bload_f32(Z2p + ((m * 4 + 0) << 9) + e)
                          + q1 * bload_f32(Z2p + ((m * 4 + 1) << 9) + e)
                          + q2 * bload_f32(Z2p + ((m * 4 + 2) << 9) + e)
                          + q3 * bload_f32(Z2p + ((m * 4 + 3) << 9) + e);
                z += num / den;
                float o = ftanh(z);
                out[((long)m * 64 + t) * 512 + e] = o;
                ((f16*)(scr + 8752))[tid] = (f16)o;
            }
            __syncthreads();
            if (tid < 32) {
                f16* ob = (f16*)(scr + 8752);
                union { f16 h[4]; u64 u; } pk;
                #pragma unroll
                for (int i = 0; i < 4; ++i) pk.h[i] = ob[tid * 4 + i];
                bstore8(Orot + (long)rs1 * 32768 + m * 512 + sq * 128 + tid * 4, pk.u);
            }
        }
        gsync(sync, ++epoch);   // B4 (drains out/Orot)
    }
}

extern "C" void kernel_launch(void* const* d_in, const int* in_sizes, int n_in,
                              void* d_out, int out_size, void* d_ws, size_t ws_size,
                              hipStream_t stream)
{
    const int*   tgt   = (const int*)d_in[0];
    const float* henc  = (const float*)d_in[1];
    const float* emb   = (const float*)d_in[2];
    const float* oinit = (const float*)d_in[3];
    const float* hinit = (const float*)d_in[4];
    const float* Wih   = (const float*)d_in[5];
    const float* Whh   = (const float*)d_in[6];
    const float* bih   = (const float*)d_in[7];
    const float* bhh   = (const float*)d_in[8];
    const float* W1    = (const float*)d_in[9];
    const float* b1    = (const float*)d_in[10];
    const float* W2    = (const float*)d_in[11];
    const float* b2    = (const float*)d_in[12];
    float* out = (float*)d_out;

    char* ws = (char*)d_ws;
    f16*      wcat  = (f16*)(ws + 0);              // 32 MB
    f16*      P16   = (f16*)(ws + 33554432);       // 16 MB
    f16*      Q216  = (f16*)(ws + 50331648);       //  8 MB
    f16*      h16   = (f16*)(ws + 58720256);       // 16 MB (gemm input; first 1 MB
                                                   //  reused by persist as Z1f/Z2p)
    f16*      w2b   = (f16*)(ws + 75497472);       //  1 MB
    f16*      w1c   = (f16*)(ws + 76546048);       //  2 MB
    f16*      w2a   = (f16*)(ws + 78643200);       //  1 MB
    f16*      Xall  = (f16*)(ws + 79691776);       //  4 MB
    f16*      H0rot = (f16*)(ws + 83886080);       //  2 MB (16 slots)
    f16*      H1rot = (f16*)(ws + 85983232);       //  2 MB
    f16*      Orot  = (f16*)(ws + 88080384);       //  1 MB
    float*    c01   = (float*)(ws + 89128960);     // 512 KB
    float*    Z1f   = (float*)(ws + 58720256);     // 512 KB (4 K-quarter slices)
    float*    Z2p   = (float*)(ws + 59244544);     // 512 KB (4 sq partials)
    float*    Z2s   = (float*)(ws + 90439680);     //   2 KB (mx,sum pairs)
    float*    bsum  = (float*)(ws + 90472448);     //  32 KB
    float*    sb    = (float*)(ws + 90505216);     //  32 KB
    unsigned* sync  = (unsigned*)(ws + 90537984);  //  12 KB: arr|rel

    hipLaunchKernelGGL(k_convert, dim3(4096), dim3(256), 0, stream,
                       Wih, Whh, W1, W2, bih, bhh, tgt, emb, henc,
                       wcat, w1c, w2a, w2b, bsum, Xall, h16);
    hipLaunchKernelGGL(k_init, dim3(1164), dim3(256), 0, stream,
                       oinit, hinit, Orot, H0rot, H1rot, c01, sync);
    hipLaunchKernelGGL(k_sb, dim3(32), dim3(256), 0, stream, b1, henc, sb);
    hipLaunchKernelGGL(k_gemm, dim3(128 * 8), dim3(256), 0, stream,
                       h16, w1c, P16, 1024);
    hipLaunchKernelGGL(k_gemm, dim3(128 * 4), dim3(256), 0, stream,
                       h16, w2a, Q216, 512);

    static const unsigned LDS_BYTES = 9472 * 4 + 32768 * 2 + 16384 * 2; // 136192
    hipFuncSetAttribute((const void*)k_persist,
                        hipFuncAttributeMaxDynamicSharedMemorySize, LDS_BYTES);
    void* args[] = { &wcat, &bsum, &c01, &Xall, &Orot, &H0rot, &H1rot, &P16,
                     &Q216, &w2b, &sb, &b2, &out, &Z1f, &Z2p, &Z2s, &sync };
    hipLaunchCooperativeKernel((const void*)k_persist, dim3(256), dim3(512),
                               args, LDS_BYTES, stream);
}